// Round 4
// baseline (111.213 us; speedup 1.0000x reference)
//
#include <hip/hip_runtime.h>
#include <stdint.h>

// IndexedLinearLayer — R13: single-node, QW=1 (16 waves), B-prefetch.
//
// R12 post-mortem: kernel 57 µs, VALU 31% / MFMA 2.7% / HBM 5.6% / occ 30%
// — latency-bound: 4 waves/SIMD and the inner loop serializes 8 scalar
// table loads -> vmcnt(0) -> pack -> MFMA. Floors: B L1-lines ~13 µs,
// VALU ~10 µs -> a pipelined kernel should be ~20 µs.
//
// R13 keeps the R12 algorithm (one node, LDS bf16-x + nibble-idx staging,
// register q-accum, LDS wave-reduce, XCD-exact table mapping, swizzles):
//  - 1024-thr blocks, wave w owns q=w (QW=1): grid 512 -> 2 blocks/CU ->
//    8 waves/SIMD (2x occupancy), per-wave loop ~2x leaner
//  - explicit B double-buffer: prefetch kb+1's 8 table scalars into regs
//    before mask/pack/MFMA of kb (hide ~200 cy L2 latency under compute)
//  - __launch_bounds__(1024, 8) pins VGPR<=64 so 8 waves/SIMD holds
// Predicted: kernel ~18-28 µs, VALUBusy ~55%, occ ~70%, total ~75-85 µs.

constexpr int SIZE_IN  = 1024;
constexpr int SIZE_OUT = 256;
constexpr int BATCH    = 512;
constexpr int NUM_Q    = 16;
constexpr int TM = 16;             // batch rows per block
constexpr int TN = 16;             // out cols per block

typedef short short8   __attribute__((ext_vector_type(8)));
typedef float floatx4  __attribute__((ext_vector_type(4)));

__device__ inline uint32_t pack2bf(float lo, float hi) {
    uint32_t a = __float_as_uint(lo) + 0x8000u;
    uint32_t b = __float_as_uint(hi) + 0x8000u;
    return __builtin_amdgcn_perm(b, a, 0x07060302);  // {hi.bf16 : lo.bf16}
}

__global__ __launch_bounds__(1024, 8)
void idxlin_q1(const float* __restrict__ x,      // [512,1024]
               const int*   __restrict__ idx,    // [512,1024]
               const float* __restrict__ table,  // [16*1024, 256]
               const float* __restrict__ bias,   // [256]
               float*       __restrict__ out)    // [512,256]
{
    __shared__ uint16_t x_lds[TM * 1024];   // bf16, row stride 2048 B, swizzled
    __shared__ uint32_t i_lds[TM * 128];    // 4-bit nibbles, row stride 512 B, swizzled
    __shared__ float    red[16][64][4];     // wave-reduce buffer (16 KB)

    const int tid = threadIdx.x;            // 0..1023

    // XCD-exact decode: blk = bt*16 + half*8 + h ; nh = 2h + half
    const int h    = blockIdx.x & 7;
    const int half = (blockIdx.x >> 3) & 1;
    const int bt   = blockIdx.x >> 4;
    const int nh   = h * 2 + half;
    const int b0   = bt * TM;
    const int n0   = nh * TN;

    // ---- Stage x -> bf16 LDS (coalesced float4) ----
    const float4* x4 = reinterpret_cast<const float4*>(x + b0 * SIZE_IN);
    char* xb = reinterpret_cast<char*>(x_lds);
    #pragma unroll
    for (int it = 0; it < 4; ++it) {
        const int u   = it * 1024 + tid;    // f4-unit 0..4095
        const int row = u >> 8;             // 256 f4 per row
        const int c8  = u & 255;
        const float4 xv = x4[u];
        uint2 d;
        d.x = pack2bf(xv.x, xv.y);
        d.y = pack2bf(xv.z, xv.w);
        const int byte = row * 2048 + ((c8 * 8) ^ ((row & 7) << 4));
        *reinterpret_cast<uint2*>(xb + byte) = d;
    }

    // ---- Stage idx -> packed nibbles in LDS (coalesced int4 pairs) ----
    const int4* i4 = reinterpret_cast<const int4*>(idx + b0 * SIZE_IN);
    char* ib = reinterpret_cast<char*>(i_lds);
    #pragma unroll
    for (int it = 0; it < 2; ++it) {
        const int u   = it * 1024 + tid;    // u32-unit 0..2047 (8 idx each)
        const int row = u >> 7;             // 128 units per row
        const int c32 = u & 127;
        const int4 a = i4[2 * u];
        const int4 b = i4[2 * u + 1];
        const uint32_t n =  (uint32_t)a.x        | ((uint32_t)a.y << 4)
                         | ((uint32_t)a.z << 8)  | ((uint32_t)a.w << 12)
                         | ((uint32_t)b.x << 16) | ((uint32_t)b.y << 20)
                         | ((uint32_t)b.z << 24) | ((uint32_t)b.w << 28);
        const int byte = row * 512 + ((c32 * 4) ^ ((row & 15) << 2));
        *reinterpret_cast<uint32_t*>(ib + byte) = n;
    }
    __syncthreads();

    // ---- MFMA K-loop: wave w owns q = w ----
    const int lane  = tid & 63;
    const int w     = tid >> 6;          // 0..15 == q
    const int nlane = lane & 15;
    const int quad  = lane >> 4;
    const uint32_t q = (uint32_t)w;

    const char* xrow = xb + nlane * 2048;
    const char* irow = ib + nlane * 512;
    const int   sx   = (nlane & 7) << 4;
    const int   si   = (nlane & 15) << 2;

    const float* bp = table + (((int)q * SIZE_IN + quad * 8) * SIZE_OUT) + n0 + nlane;

    floatx4 acc = {0.f, 0.f, 0.f, 0.f};

    float wv[8];
    #pragma unroll
    for (int j = 0; j < 8; ++j) wv[j] = bp[j * SIZE_OUT];

    #pragma unroll 4
    for (int kb = 0; kb < SIZE_IN / 32; ++kb) {
        // prefetch next kb's B scalars (hide L2 latency under this kb)
        const float* bn = bp + 32 * SIZE_OUT;
        float wn[8];
        if (kb < SIZE_IN / 32 - 1) {
            #pragma unroll
            for (int j = 0; j < 8; ++j) wn[j] = bn[j * SIZE_OUT];
        } else {
            #pragma unroll
            for (int j = 0; j < 8; ++j) wn[j] = 0.f;
        }

        // A fragment + nibble word from LDS
        union { uint32_t u[4]; short8 s; } ar;
        ar.s = *reinterpret_cast<const short8*>(xrow + ((kb * 64 + quad * 16) ^ sx));
        const uint32_t nib = *reinterpret_cast<const uint32_t*>(
                                 irow + ((kb * 16 + quad * 4) ^ si));

        // per-q mask (bf16 halves zeroed where idx != q)
        union { uint32_t u[4]; short8 s; } af;
        #pragma unroll
        for (int p = 0; p < 4; ++p) {
            const uint32_t e0 = (nib >> (8 * p)) & 15u;
            const uint32_t e1 = (nib >> (8 * p + 4)) & 15u;
            const uint32_t msk = (e0 == q ? 0x0000FFFFu : 0u)
                               | (e1 == q ? 0xFFFF0000u : 0u);
            af.u[p] = ar.u[p] & msk;
        }

        // pack current B scalars and MFMA
        union { uint32_t u[4]; short8 s; } bf;
        bf.u[0] = pack2bf(wv[0], wv[1]);
        bf.u[1] = pack2bf(wv[2], wv[3]);
        bf.u[2] = pack2bf(wv[4], wv[5]);
        bf.u[3] = pack2bf(wv[6], wv[7]);

        acc = __builtin_amdgcn_mfma_f32_16x16x32_bf16(af.s, bf.s, acc, 0, 0, 0);

        #pragma unroll
        for (int j = 0; j < 8; ++j) wv[j] = wn[j];
        bp = bn;
    }

    // ---- reduce 16 waves' accs in LDS, add bias, write ----
    #pragma unroll
    for (int rr = 0; rr < 4; ++rr) red[w][lane][rr] = acc[rr];
    __syncthreads();

    if (tid < 256) {
        const int l  = tid >> 2;         // lane id 0..63
        const int rr = tid & 3;          // acc reg
        float s = red[0][l][rr];
        #pragma unroll
        for (int ww = 1; ww < 16; ++ww) s += red[ww][l][rr];
        const int row = b0 + (l >> 4) * 4 + rr;   // C/D: row = quad*4 + reg
        const int col = n0 + (l & 15);            //      col = nlane
        out[row * SIZE_OUT + col] = s + bias[col];
    }
}

extern "C" void kernel_launch(void* const* d_in, const int* in_sizes, int n_in,
                              void* d_out, int out_size, void* d_ws, size_t ws_size,
                              hipStream_t stream) {
    const float* x     = (const float*)d_in[0];
    const int*   idx   = (const int*)d_in[1];
    const float* table = (const float*)d_in[2];
    const float* bias  = (const float*)d_in[3];
    float*       out   = (float*)d_out;
    (void)d_ws; (void)ws_size;

    idxlin_q1<<<dim3((BATCH / TM) * (SIZE_OUT / TN)), dim3(1024), 0, stream>>>(
        x, idx, table, bias, out);
}

// Round 5
// 89.695 us; speedup vs baseline: 1.2399x; 1.2399x over previous
//
#include <hip/hip_runtime.h>
#include <stdint.h>

// IndexedLinearLayer as implicit-A GEMM, 2-kernel pipeline (R3 config —
// session-best: 88.4 µs prior session, 90.0 µs this session R9):
//   K1: per-(bt,nh,q) block: mask x tile in-LDS -> A' (bf16), read B (fp32)
//       scalar + pack bf16, MFMA 16x16x32, write split-q partials to ws
//   K2: reduce 16 partials + bias -> out
//
// R14 rationale (final revert): the harness's two unconditional 256-MiB
// ws-poison fills are 512 MiB of mandatory HBM writes at ~77-79% of peak
// = 85-87 µs/iter — the structural floor. Model over R9-R13:
//   2-node light kernels (this config): total = fills + ~3 µs  -> 88-90
//   1-node wide kernels: total = fills + ~0.4-0.7 x kernel_standalone
//     (CU contention with the fills; R12/R13's 54-57 µs kernel -> 110-111,
//      and the kernel-standalone floor is L1-segment-bound at ~15-20 µs,
//      projecting ~95+ — strictly worse than this 2-node config).
// This config's kernels (2 blocks/CU, 8 waves/CU, BW-light) hide inside
// the fills' BW-stall slack. Predicted: fills top-2 @~43.5 µs, dur 88-90.

constexpr int SIZE_IN  = 1024;
constexpr int SIZE_OUT = 256;
constexpr int BATCH    = 512;
constexpr int NUM_Q    = 16;
constexpr int TM = 32;             // batch tile
constexpr int TN = 128;            // out tile
constexpr int A_STRIDE = 1032;     // bf16 elems/row, +8 pad

constexpr size_t WS_NEED = (size_t)NUM_Q * BATCH * SIZE_OUT * sizeof(float); // 8 MB

typedef short short8   __attribute__((ext_vector_type(8)));
typedef float floatx4  __attribute__((ext_vector_type(4)));

__device__ inline uint32_t pack2bf(float lo, float hi) {
    uint32_t a = __float_as_uint(lo) + 0x8000u;
    uint32_t b = __float_as_uint(hi) + 0x8000u;
    return __builtin_amdgcn_perm(b, a, 0x07060302);  // {b.hi16, a.hi16}
}

template <bool USE_WS>
__global__ __launch_bounds__(256, 2)
void idxlin_mfma(const float* __restrict__ x,      // [512,1024]
                 const int*   __restrict__ idx,    // [512,1024]
                 const float* __restrict__ table,  // [16*1024, 256]
                 const float* __restrict__ bias,   // [256]
                 float*       __restrict__ out,    // [512,256] (atomic path: pre-zeroed)
                 float*       __restrict__ ws)     // [16,512,256] partials (ws path)
{
    __shared__ uint16_t Alds[TM * A_STRIDE];       // 66 KB -> 2 blocks/CU

    const int tid = threadIdx.x;
    const int q   = blockIdx.x & 15;               // XCD = blockIdx%8 = q%8
    const int r   = blockIdx.x >> 4;
    const int nh  = r & 1;
    const int bt  = r >> 1;
    const int b0  = bt * TM;
    const int n0  = nh * TN;

    // ---- Stage masked-x A-tile into LDS (bf16). Iter s fills row m=s. ----
    const float4* x4 = reinterpret_cast<const float4*>(x   + b0 * SIZE_IN);
    const int4*   i4 = reinterpret_cast<const int4*>(idx + b0 * SIZE_IN);
    #pragma unroll 4
    for (int s = 0; s < TM; ++s) {
        const int f = s * 256 + tid;
        const float4 xv = x4[f];
        const int4   iv = i4[f];
        const float v0 = (iv.x == q) ? xv.x : 0.f;
        const float v1 = (iv.y == q) ? xv.y : 0.f;
        const float v2 = (iv.z == q) ? xv.z : 0.f;
        const float v3 = (iv.w == q) ? xv.w : 0.f;
        uint2 d;
        d.x = pack2bf(v0, v1);
        d.y = pack2bf(v2, v3);
        *reinterpret_cast<uint2*>(&Alds[s * A_STRIDE + tid * 4]) = d;
    }
    __syncthreads();

    // ---- MFMA K-loop ----
    const int lane  = tid & 63;
    const int w     = tid >> 6;        // wave: owns out cols [n0+w*32, +32)
    const int nlane = lane & 15;
    const int quad  = lane >> 4;

    const float* bp = table + (q * SIZE_IN + quad * 8) * SIZE_OUT + n0 + w * 32 + nlane;
    const uint16_t* arow0 = &Alds[(0 * 16 + nlane) * A_STRIDE + quad * 8];
    const uint16_t* arow1 = &Alds[(1 * 16 + nlane) * A_STRIDE + quad * 8];

    floatx4 acc[2][2] = {{{0.f,0.f,0.f,0.f},{0.f,0.f,0.f,0.f}},
                         {{0.f,0.f,0.f,0.f},{0.f,0.f,0.f,0.f}}};

    #pragma unroll 2
    for (int kb = 0; kb < SIZE_IN / 32; ++kb) {
        float wv[2][8];
        #pragma unroll
        for (int nt = 0; nt < 2; ++nt)
            #pragma unroll
            for (int j = 0; j < 8; ++j)
                wv[nt][j] = bp[j * SIZE_OUT + nt * 16];

        const short8 a0 = *reinterpret_cast<const short8*>(arow0 + kb * 32);
        const short8 a1 = *reinterpret_cast<const short8*>(arow1 + kb * 32);

        #pragma unroll
        for (int nt = 0; nt < 2; ++nt) {
            union { uint32_t u[4]; short8 s; } bf;
            bf.u[0] = pack2bf(wv[nt][0], wv[nt][1]);
            bf.u[1] = pack2bf(wv[nt][2], wv[nt][3]);
            bf.u[2] = pack2bf(wv[nt][4], wv[nt][5]);
            bf.u[3] = pack2bf(wv[nt][6], wv[nt][7]);
            acc[0][nt] = __builtin_amdgcn_mfma_f32_16x16x32_bf16(a0, bf.s, acc[0][nt], 0, 0, 0);
            acc[1][nt] = __builtin_amdgcn_mfma_f32_16x16x32_bf16(a1, bf.s, acc[1][nt], 0, 0, 0);
        }
        bp += 32 * SIZE_OUT;
    }

    // ---- Split-K output. C/D layout: col = lane&15, row = quad*4 + reg ----
    if (USE_WS) {
        float* wsq = ws + ((size_t)(q * BATCH + b0)) * SIZE_OUT + n0;
        #pragma unroll
        for (int mt = 0; mt < 2; ++mt)
            #pragma unroll
            for (int nt = 0; nt < 2; ++nt)
                #pragma unroll
                for (int rr = 0; rr < 4; ++rr) {
                    const int row = mt * 16 + quad * 4 + rr;
                    const int col = w * 32 + nt * 16 + nlane;
                    wsq[row * SIZE_OUT + col] = acc[mt][nt][rr];
                }
    } else {
        #pragma unroll
        for (int mt = 0; mt < 2; ++mt)
            #pragma unroll
            for (int nt = 0; nt < 2; ++nt)
                #pragma unroll
                for (int rr = 0; rr < 4; ++rr) {
                    const int bg = b0 + mt * 16 + quad * 4 + rr;
                    const int o  = n0 + w * 32 + nt * 16 + nlane;
                    atomicAdd(&out[bg * SIZE_OUT + o], acc[mt][nt][rr]);
                }
        if (q == 0) {
            const int o_l = tid & (TN - 1);
            const int m0  = (tid >> 7) * 16;
            const float bv = bias[n0 + o_l];
            #pragma unroll
            for (int rr = 0; rr < 16; ++rr)
                atomicAdd(&out[(b0 + m0 + rr) * SIZE_OUT + n0 + o_l], bv);
        }
    }
}

// Sum 16 q-partials + bias. Flat float4 index e over [512 b][64 o4].
__global__ __launch_bounds__(256)
void reduce_ws(const float* __restrict__ ws, const float* __restrict__ bias,
               float* __restrict__ out)
{
    const int e  = blockIdx.x * 256 + threadIdx.x;      // 0..32767
    const int o4 = e & 63;
    const float4* w4 = reinterpret_cast<const float4*>(ws);
    float4 s = reinterpret_cast<const float4*>(bias)[o4];
    #pragma unroll
    for (int q = 0; q < NUM_Q; ++q) {
        const float4 v = w4[(size_t)q * (BATCH * SIZE_OUT / 4) + e];
        s.x += v.x; s.y += v.y; s.z += v.z; s.w += v.w;
    }
    reinterpret_cast<float4*>(out)[e] = s;
}

extern "C" void kernel_launch(void* const* d_in, const int* in_sizes, int n_in,
                              void* d_out, int out_size, void* d_ws, size_t ws_size,
                              hipStream_t stream) {
    const float* x     = (const float*)d_in[0];
    const int*   idx   = (const int*)d_in[1];
    const float* table = (const float*)d_in[2];
    const float* bias  = (const float*)d_in[3];
    float*       out   = (float*)d_out;
    float*       ws    = (float*)d_ws;

    if (ws_size >= WS_NEED) {
        idxlin_mfma<true><<<dim3(512), dim3(256), 0, stream>>>(x, idx, table, bias, out, ws);
        reduce_ws<<<dim3(BATCH * SIZE_OUT / 4 / 256), dim3(256), 0, stream>>>(ws, bias, out);
    } else {
        hipMemsetAsync(out, 0, (size_t)out_size * sizeof(float), stream);
        idxlin_mfma<false><<<dim3(512), dim3(256), 0, stream>>>(x, idx, table, bias, out, ws);
    }
}